// Round 1
// baseline (865.630 us; speedup 1.0000x reference)
//
#include <hip/hip_runtime.h>
#include <math.h>

#define NN 255
#define MM 300
#define TC 510   // total columns = 2 trees * 255 nodes

__device__ __forceinline__ float sigm(float x) { return 1.0f / (1.0f + expf(-x)); }

// gate a leaf node purely from its xg row (children are zero)
__device__ __forceinline__ void leaf_gate(const float* __restrict__ xgp, int m, float& c, float& h) {
  float x0 = xgp[m], x1 = xgp[300 + m], x3 = xgp[900 + m];
  float u  = tanhf(x0);
  float ig = sigm(x1);
  c = ig * u;
  h = sigm(x3) * tanhf(c);
}

// ---------------- setup: node levels + per-level node lists ----------------
__global__ __launch_bounds__(512) void k_setup(const int* __restrict__ l1, const int* __restrict__ r1,
                                               const int* __restrict__ l2, const int* __restrict__ r2,
                                               int* __restrict__ lists, int* __restrict__ cnt)
{
  __shared__ int lv[TC];
  __shared__ int cs[16];
  int t = threadIdx.x;
  if (t < TC) lv[t] = 0;
  if (t < 16) cs[t] = 0;
  __syncthreads();
  for (int it = 0; it < 12; ++it) {   // parallel relaxation; depth of balanced tree = 7
    int nv = 0;
    if (t < TC) {
      int tr = t >= NN;
      int i  = t - tr * NN;
      const int* L = tr ? l2 : l1;
      const int* R = tr ? r2 : r1;
      int l = L[i], r = R[i];
      nv = (l < 0) ? 0 : 1 + max(lv[tr * NN + l], lv[tr * NN + r]);
    }
    __syncthreads();
    if (t < TC) lv[t] = nv;
    __syncthreads();
  }
  if (t < TC) {
    int tr = t >= NN;
    int i  = t - tr * NN;
    int v  = min(lv[t], 15);
    int pos = atomicAdd(&cs[v], 1);
    lists[v * 256 + pos] = (tr << 8) | i;
  }
  __syncthreads();
  if (t < 16) cnt[t] = cs[t];
}

// ---------------- xg GEMM: out[col][r] = bias[r] + sum_d W[r][d] * Z[col][d] ----------------
// Z = emb[tok] (hsrc==null) or hsrc rows (compare stage). R=1200, K=300.
__global__ __launch_bounds__(256) void k_xg(const int* __restrict__ sent1, const int* __restrict__ sent2,
                                            const int* __restrict__ l1, const int* __restrict__ l2,
                                            const float* __restrict__ emb, int pad,
                                            const float* __restrict__ W, const float* __restrict__ bias,
                                            const float* __restrict__ hsrc, float* __restrict__ out)
{
  __shared__ float Z[8][300];
  int tx = threadIdx.x, ty = threadIdx.y;
  int t = ty * 64 + tx;
  int colbase = blockIdx.y * 8;
  for (int c = 0; c < 8; ++c) {
    int gcol = colbase + c;
    if (gcol < TC) {
      if (hsrc) {
        for (int k = t; k < 300; k += 256) Z[c][k] = hsrc[(size_t)gcol * 300 + k];
      } else {
        int tr = gcol >= NN;
        int node = gcol - tr * NN;
        const int* L = tr ? l2 : l1;
        const int* S = tr ? sent2 : sent1;
        int tok = (L[node] < 0) ? S[node] : pad;
        const float* e = emb + (size_t)tok * 300;
        for (int k = t; k < 300; k += 256) Z[c][k] = e[k];
      }
    } else {
      for (int k = t; k < 300; k += 256) Z[c][k] = 0.f;
    }
  }
  __syncthreads();
  int r = blockIdx.x * 64 + tx;
  if (r < 1200) {
    float a0 = 0.f, a1 = 0.f;
    const float* wp = W + (size_t)r * 300;
    for (int k = 0; k < 300; k += 4) {
      float4 wv = *(const float4*)(wp + k);
      float4 z0 = *(const float4*)(&Z[ty][k]);
      float4 z1 = *(const float4*)(&Z[ty + 4][k]);
      a0 += wv.x*z0.x + wv.y*z0.y + wv.z*z0.z + wv.w*z0.w;
      a1 += wv.x*z1.x + wv.y*z1.y + wv.z*z1.z + wv.w*z1.w;
    }
    float b = bias[r];
    int g0 = colbase + ty, g1 = colbase + ty + 4;
    if (g0 < TC) out[(size_t)g0 * 1200 + r] = a0 + b;
    if (g1 < TC) out[(size_t)g1 * 1200 + r] = a1 + b;
  }
}

// ---------------- per-level tree-LSTM kernel ----------------
// GEMM G[node][(j,m)] = sum_d Wl[j,m,d]*H[left] + Wr[j,m,d]*H[right], then last
// row-block per column-tile performs the gating for those nodes (split-K tail).
__global__ __launch_bounds__(256) void k_level(const int* __restrict__ l1, const int* __restrict__ r1,
                                               const int* __restrict__ l2, const int* __restrict__ r2,
                                               const float* __restrict__ Wl, const float* __restrict__ Wr,
                                               const float* __restrict__ xg,
                                               float* __restrict__ H, float* __restrict__ C, float* __restrict__ G,
                                               const int* __restrict__ lists, const int* __restrict__ cnt,
                                               int* __restrict__ ctr, int level, int ctrBase)
{
  __shared__ float Z[8][600];
  __shared__ int lastFlag;
  int tx = threadIdx.x, ty = threadIdx.y;
  int t = ty * 64 + tx;
  int ncols = cnt[level];
  int colbase = blockIdx.y * 8;

  // stage children H (leaves gated inline from xg; block x==0 publishes leaf H)
  for (int c = 0; c < 8; ++c) {
    int gcol = colbase + c;
    if (gcol < ncols) {
      int e = lists[level * 256 + gcol];
      int tr = e >> 8, node = e & 255;
      const int* L = tr ? l2 : l1;
      const int* R = tr ? r2 : r1;
      int lch = L[node], rch = R[node];
      for (int k = t; k < 600; k += 256) {
        int child = (k < 300) ? lch : rch;
        int kk    = (k < 300) ? k : k - 300;
        int ci = tr * NN + child;
        float h;
        if (L[child] < 0) {
          float cd;
          leaf_gate(xg + (size_t)ci * 1200, kk, cd, h);
          if (blockIdx.x == 0) H[(size_t)ci * 300 + kk] = h;
        } else {
          h = H[(size_t)ci * 300 + kk];
        }
        Z[c][k] = h;
      }
    } else {
      for (int k = t; k < 600; k += 256) Z[c][k] = 0.f;
    }
  }
  __syncthreads();

  int r = blockIdx.x * 64 + tx;
  if (r < 1500) {
    float a0 = 0.f, a1 = 0.f;
    const float* wl = Wl + (size_t)r * 300;
    const float* wr = Wr + (size_t)r * 300;
    for (int k = 0; k < 300; k += 4) {
      float4 wv = *(const float4*)(wl + k);
      float4 z0 = *(const float4*)(&Z[ty][k]);
      float4 z1 = *(const float4*)(&Z[ty + 4][k]);
      a0 += wv.x*z0.x + wv.y*z0.y + wv.z*z0.z + wv.w*z0.w;
      a1 += wv.x*z1.x + wv.y*z1.y + wv.z*z1.z + wv.w*z1.w;
    }
    for (int k = 0; k < 300; k += 4) {
      float4 wv = *(const float4*)(wr + k);
      float4 z0 = *(const float4*)(&Z[ty][300 + k]);
      float4 z1 = *(const float4*)(&Z[ty + 4][300 + k]);
      a0 += wv.x*z0.x + wv.y*z0.y + wv.z*z0.z + wv.w*z0.w;
      a1 += wv.x*z1.x + wv.y*z1.y + wv.z*z1.z + wv.w*z1.w;
    }
    int g0 = colbase + ty, g1 = colbase + ty + 4;
    if (g0 < ncols) { int e = lists[level*256+g0]; int gi = (e>>8)*NN + (e&255); G[(size_t)gi*1500 + r] = a0; }
    if (g1 < ncols) { int e = lists[level*256+g1]; int gi = (e>>8)*NN + (e&255); G[(size_t)gi*1500 + r] = a1; }
  }

  // release my G writes, count down; last row-block gates this column tile
  __threadfence();
  __syncthreads();
  if (t == 0) {
    int old = atomicAdd(&ctr[ctrBase + blockIdx.y], 1);
    lastFlag = (old == (int)gridDim.x - 1) ? 1 : 0;
  }
  __syncthreads();
  if (lastFlag) {
    __threadfence();  // acquire: see all row-blocks' G writes
    for (int task = t; task < 2400; task += 256) {
      int c = task / 300;
      int m = task - c * 300;
      int gcol = colbase + c;
      if (gcol >= ncols) continue;
      int e = lists[level * 256 + gcol];
      int tr = e >> 8, node = e & 255;
      const int* L = tr ? l2 : l1;
      const int* R = tr ? r2 : r1;
      int lch = L[node], rch = R[node];
      int gi = tr * NN + node;
      const float* Gp = G + (size_t)gi * 1500;
      const float* xp = xg + (size_t)gi * 1200;
      float lc, rc, hd;
      if (L[lch] < 0) leaf_gate(xg + (size_t)(tr*NN+lch)*1200, m, lc, hd);
      else            lc = C[(size_t)(tr*NN+lch)*300 + m];
      if (L[rch] < 0) leaf_gate(xg + (size_t)(tr*NN+rch)*1200, m, rc, hd);
      else            rc = C[(size_t)(tr*NN+rch)*300 + m];
      float u  = tanhf(xp[m]       + Gp[m]);
      float ig = sigm (xp[300 + m] + Gp[300 + m]);
      float lf = sigm (xp[600 + m] + Gp[600 + m]);
      float rf = sigm (xp[600 + m] + Gp[900 + m]);   // fx shared for both forgets
      float o  = sigm (xp[900 + m] + Gp[1200 + m]);
      float cc = ig * u + lf * lc + rf * rc;
      C[(size_t)gi * 300 + m] = cc;
      H[(size_t)gi * 300 + m] = o * tanhf(cc);
    }
  }
}

// ---------------- attention: one block per output row (beta rows then alpha rows) ----------------
__global__ __launch_bounds__(256) void k_attn(const float* __restrict__ Henc, float* __restrict__ ab)
{
  __shared__ float q[300];
  __shared__ float pr[NN];
  __shared__ float red[256];
  int b = blockIdx.x, t = threadIdx.x;
  int dir = b >= NN;
  int i = b - dir * NN;
  const float* Ss = Henc + (dir ? NN * 300 : 0);
  const float* So = Henc + (dir ? 0 : NN * 300);
  for (int k = t; k < 300; k += 256) q[k] = Ss[(size_t)i * 300 + k];
  __syncthreads();
  float v = -1e30f;
  if (t < NN) {
    const float* row = So + (size_t)t * 300;
    float a = 0.f;
    for (int k = 0; k < 300; k += 4) {
      float4 rv = *(const float4*)(row + k);
      float4 qv = *(const float4*)(&q[k]);
      a += rv.x*qv.x + rv.y*qv.y + rv.z*qv.z + rv.w*qv.w;
    }
    pr[t] = a;
    v = a;
  }
  red[t] = v;
  __syncthreads();
  for (int s = 128; s > 0; s >>= 1) { if (t < s) red[t] = fmaxf(red[t], red[t + s]); __syncthreads(); }
  float mx = red[0];
  __syncthreads();
  float e = 0.f;
  if (t < NN) { e = expf(pr[t] - mx); pr[t] = e; }
  red[t] = e;
  __syncthreads();
  for (int s = 128; s > 0; s >>= 1) { if (t < s) red[t] += red[t + s]; __syncthreads(); }
  float inv = 1.0f / red[0];
  __syncthreads();
  for (int m = t; m < 300; m += 256) {
    float a = 0.f;
    for (int j = 0; j < NN; ++j) a += pr[j] * So[(size_t)j * 300 + m];
    ab[(size_t)b * 300 + m] = a * inv;
  }
}

// ---------------- compare h: h = relu(Wc @ [s,a,s-a,s*a] + bc). R=300, K=1200 ----------------
__global__ __launch_bounds__(256) void k_hcmp(const float* __restrict__ Henc, const float* __restrict__ ab,
                                              const float* __restrict__ Wc, const float* __restrict__ bc,
                                              float* __restrict__ hc)
{
  __shared__ float Z[8][1200];
  int tx = threadIdx.x, ty = threadIdx.y;
  int t = ty * 64 + tx;
  int colbase = blockIdx.y * 8;
  for (int c = 0; c < 8; ++c) {
    int gcol = colbase + c;
    if (gcol < TC) {
      const float* sp = Henc + (size_t)gcol * 300;
      const float* ap = ab + (size_t)gcol * 300;
      for (int k = t; k < 1200; k += 256) {
        int sel = k >= 900 ? 3 : (k >= 600 ? 2 : (k >= 300 ? 1 : 0));
        int kk = k - sel * 300;
        float s = sp[kk], a = ap[kk];
        Z[c][k] = sel == 0 ? s : sel == 1 ? a : sel == 2 ? (s - a) : (s * a);
      }
    } else {
      for (int k = t; k < 1200; k += 256) Z[c][k] = 0.f;
    }
  }
  __syncthreads();
  int r = blockIdx.x * 64 + tx;
  if (r < 300) {
    float a0 = 0.f, a1 = 0.f;
    const float* wp = Wc + (size_t)r * 1200;
    for (int k = 0; k < 1200; k += 4) {
      float4 wv = *(const float4*)(wp + k);
      float4 z0 = *(const float4*)(&Z[ty][k]);
      float4 z1 = *(const float4*)(&Z[ty + 4][k]);
      a0 += wv.x*z0.x + wv.y*z0.y + wv.z*z0.z + wv.w*z0.w;
      a1 += wv.x*z1.x + wv.y*z1.y + wv.z*z1.z + wv.w*z1.w;
    }
    float b = bc[r];
    int g0 = colbase + ty, g1 = colbase + ty + 4;
    if (g0 < TC) hc[(size_t)g0 * 300 + r] = fmaxf(a0 + b, 0.f);
    if (g1 < TC) hc[(size_t)g1 * 300 + r] = fmaxf(a1 + b, 0.f);
  }
}

// ---------------- aggregate: mean/max over nodes per tree ----------------
__global__ __launch_bounds__(256) void k_agg(const float* __restrict__ Hcmp, float* __restrict__ agg)
{
  int tr = blockIdx.x, t = threadIdx.x;
  for (int m = t; m < 300; m += 256) {
    float s = 0.f, mx = -1e30f;
    const float* hp = Hcmp + (size_t)tr * NN * 300 + m;
    for (int n = 0; n < NN; ++n) { float v = hp[(size_t)n * 300]; s += v; mx = fmaxf(mx, v); }
    agg[tr * 600 + m] = s / 255.0f;
    agg[tr * 600 + 300 + m] = mx;
  }
}

// ---------------- MLP head: hidden = relu(Wa1 @ agg + ba1); logits = Wa2 @ hidden + ba2 ----------------
__global__ __launch_bounds__(512) void k_mlp(const float* __restrict__ agg,
                                             const float* __restrict__ Wa1, const float* __restrict__ ba1,
                                             const float* __restrict__ Wa2, const float* __restrict__ ba2,
                                             float* __restrict__ out)
{
  __shared__ float a_s[1200];
  __shared__ float hid[300];
  int t = threadIdx.x;
  for (int k = t; k < 1200; k += 512) a_s[k] = agg[k];
  __syncthreads();
  for (int h = t; h < 300; h += 512) {
    float acc = ba1[h];
    const float* wp = Wa1 + (size_t)h * 1200;
    for (int k = 0; k < 1200; k += 4) {
      float4 wv = *(const float4*)(wp + k);
      float4 av = *(const float4*)(&a_s[k]);
      acc += wv.x*av.x + wv.y*av.y + wv.z*av.z + wv.w*av.w;
    }
    hid[h] = fmaxf(acc, 0.f);
  }
  __syncthreads();
  if (t < 192) {
    int c = t >> 6, lane = t & 63;
    float a = 0.f;
    for (int k = lane; k < 300; k += 64) a += Wa2[c * 300 + k] * hid[k];
    for (int off = 32; off > 0; off >>= 1) a += __shfl_down(a, off);
    if (lane == 0) out[c] = a + ba2[c];
  }
}

extern "C" void kernel_launch(void* const* d_in, const int* in_sizes, int n_in,
                              void* d_out, int out_size, void* d_ws, size_t ws_size,
                              hipStream_t stream)
{
  const int*   sent1 = (const int*)d_in[0];
  const int*   sent2 = (const int*)d_in[1];
  const int*   l1    = (const int*)d_in[2];
  const int*   r1    = (const int*)d_in[3];
  const int*   l2    = (const int*)d_in[4];
  const int*   r2    = (const int*)d_in[5];
  const float* emb   = (const float*)d_in[6];
  const float* Wx_i  = (const float*)d_in[7];
  const float* bx_i  = (const float*)d_in[8];
  const float* Wl_i  = (const float*)d_in[9];
  const float* Wr_i  = (const float*)d_in[10];
  const float* Wx_c  = (const float*)d_in[11];
  const float* bx_c  = (const float*)d_in[12];
  const float* Wl_c  = (const float*)d_in[13];
  const float* Wr_c  = (const float*)d_in[14];
  const float* Wc    = (const float*)d_in[15];
  const float* bc    = (const float*)d_in[16];
  const float* Wa1   = (const float*)d_in[17];
  const float* ba1   = (const float*)d_in[18];
  const float* Wa2   = (const float*)d_in[19];
  const float* ba2   = (const float*)d_in[20];
  int V = in_sizes[6] / 300;
  int pad = V - 1;

  char* w = (char*)d_ws;
  int* ctr   = (int*)w;                 // 256 ints  (stage*128 + level*16 + coltile)
  int* cnt   = (int*)(w + 1024);        // 16 ints
  int* lists = (int*)(w + 2048);        // 16*256 ints
  float* xg   = (float*)(w + 2048 + 16384);  // [510][1200]
  float* G    = xg + 612000;                 // [510][1500]
  float* Henc = G + 765000;                  // [510][300]
  float* Hcmp = Henc + 153000;               // [510][300]
  float* C    = Hcmp + 153000;               // [510][300]  (shared across stages)
  float* ab   = C + 153000;                  // [510][300]  beta rows then alpha rows
  float* hc   = ab + 153000;                 // [510][300]
  float* agg  = hc + 153000;                 // [1200]

  hipMemsetAsync(ctr, 0, 1024, stream);
  k_setup<<<1, 512, 0, stream>>>(l1, r1, l2, r2, lists, cnt);

  dim3 blk(64, 4);
  static const int ct[8] = {0, 16, 8, 4, 2, 1, 1, 1};  // column tiles per level (balanced tree)

  // encode stage
  k_xg<<<dim3(19, 64), blk, 0, stream>>>(sent1, sent2, l1, l2, emb, pad, Wx_i, bx_i, nullptr, xg);
  for (int d = 1; d <= 7; ++d)
    k_level<<<dim3(24, ct[d]), blk, 0, stream>>>(l1, r1, l2, r2, Wl_i, Wr_i, xg, Henc, C, G,
                                                 lists, cnt, ctr, d, d * 16);
  // attention
  k_attn<<<TC, 256, 0, stream>>>(Henc, ab);

  // compare stage
  k_hcmp<<<dim3(5, 64), blk, 0, stream>>>(Henc, ab, Wc, bc, hc);
  k_xg<<<dim3(19, 64), blk, 0, stream>>>(sent1, sent2, l1, l2, emb, pad, Wx_c, bx_c, hc, xg);
  for (int d = 1; d <= 7; ++d)
    k_level<<<dim3(24, ct[d]), blk, 0, stream>>>(l1, r1, l2, r2, Wl_c, Wr_c, xg, Hcmp, C, G,
                                                 lists, cnt, ctr, d, 128 + d * 16);

  // head
  k_agg<<<2, 256, 0, stream>>>(Hcmp, agg);
  k_mlp<<<1, 512, 0, stream>>>(agg, Wa1, ba1, Wa2, ba2, (float*)d_out);
}